// Round 1
// baseline (877.227 us; speedup 1.0000x reference)
//
#include <hip/hip_runtime.h>

// Problem constants
constexpr int B_    = 8;
constexpr int IN_C_ = 64;
constexpr int IN_L_ = 64;
constexpr int T_    = 256;
constexpr int OUT_C_ = 64;
constexpr int OUT_L_ = 64;
constexpr float EPS_ = 1e-5f;

// ---------------------------------------------------------------------------
// Kernel 1: locally-connected 3x3 conv + bias.
// grid = B*OUT_L (512) blocks, block = 256 threads (thread = t).
// Each thread accumulates all 64 output channels in registers.
// Weight accesses are block-uniform -> scalar loads (broadcast).
// ---------------------------------------------------------------------------
__global__ __launch_bounds__(256) void conv_kernel(
    const float* __restrict__ x, const float* __restrict__ w,
    const float* __restrict__ bias, float* __restrict__ out) {
  const int blk = blockIdx.x;        // 0..511
  const int b = blk >> 6;
  const int l = blk & 63;
  const int t = threadIdx.x;         // 0..255

  float acc[OUT_C_];
#pragma unroll
  for (int c = 0; c < OUT_C_; ++c) acc[c] = 0.f;

  const float* xb = x + ((size_t)b * IN_C_) * IN_L_ * T_;
  const bool l0 = (l >= 1);
  const bool l2 = (l + 1 < IN_L_);
  const bool t0 = (t >= 1);
  const bool t2 = (t + 1 < T_);

  for (int ic = 0; ic < IN_C_; ++ic) {
    const float* xr = xb + ((size_t)ic * IN_L_ + l) * T_ + t;  // center
    float xv[9];
    xv[0] = (l0 && t0) ? xr[-T_ - 1] : 0.f;   // (i=0,j=0) -> x[l-1,t-1]
    xv[1] =  l0        ? xr[-T_    ] : 0.f;   // (0,1)
    xv[2] = (l0 && t2) ? xr[-T_ + 1] : 0.f;   // (0,2)
    xv[3] =  t0        ? xr[-1     ] : 0.f;   // (1,0)
    xv[4] =              xr[ 0     ];         // (1,1)
    xv[5] =  t2        ? xr[ 1     ] : 0.f;   // (1,2)
    xv[6] = (l2 && t0) ? xr[ T_ - 1] : 0.f;   // (2,0)
    xv[7] =  l2        ? xr[ T_    ] : 0.f;   // (2,1)
    xv[8] = (l2 && t2) ? xr[ T_ + 1] : 0.f;   // (2,2)

    // w[k][c][l] flat: (k*OUT_C + c)*OUT_L + l, k = ic*9 + kk
    const float* wp = w + ((size_t)ic * 9) * (OUT_C_ * OUT_L_) + l;
#pragma unroll
    for (int kk = 0; kk < 9; ++kk) {
      const float* wk = wp + kk * (OUT_C_ * OUT_L_);
      const float xvk = xv[kk];
#pragma unroll
      for (int c = 0; c < OUT_C_; ++c) {
        acc[c] = fmaf(xvk, wk[c * OUT_L_], acc[c]);
      }
    }
  }

  const size_t obase = (((size_t)b * OUT_C_) * OUT_L_ + l) * T_ + t;
#pragma unroll
  for (int c = 0; c < OUT_C_; ++c) {
    out[obase + (size_t)c * (OUT_L_ * T_)] = acc[c] + bias[c * OUT_L_ + l];
  }
}

// ---------------------------------------------------------------------------
// Kernel 2: per-(b,c) partial sum / sumsq over the contiguous L*T chunk.
// grid = B*OUT_C (512), block = 256. part[0..511]=sum, part[512..1023]=sumsq.
// ---------------------------------------------------------------------------
__global__ __launch_bounds__(256) void stats_partial(
    const float* __restrict__ out, float* __restrict__ part) {
  const int blk = blockIdx.x;  // == b*OUT_C + c, matches memory layout
  const float4* p = (const float4*)(out + (size_t)blk * (OUT_L_ * T_));
  float s = 0.f, s2 = 0.f;
  constexpr int N4 = (OUT_L_ * T_) / 4;  // 4096
  for (int i = threadIdx.x; i < N4; i += 256) {
    float4 v = p[i];
    s  += v.x + v.y + v.z + v.w;
    s2 += v.x * v.x + v.y * v.y + v.z * v.z + v.w * v.w;
  }
#pragma unroll
  for (int off = 32; off; off >>= 1) {
    s  += __shfl_down(s, off);
    s2 += __shfl_down(s2, off);
  }
  __shared__ float ls[4], ls2[4];
  const int wid = threadIdx.x >> 6;
  const int lane = threadIdx.x & 63;
  if (lane == 0) { ls[wid] = s; ls2[wid] = s2; }
  __syncthreads();
  if (threadIdx.x == 0) {
    part[blk]       = ls[0] + ls[1] + ls[2] + ls[3];
    part[512 + blk] = ls2[0] + ls2[1] + ls2[2] + ls2[3];
  }
}

// ---------------------------------------------------------------------------
// Kernel 3: finalize per-channel scale/shift. 1 block, 64 threads.
// scaleshift[c] = gamma*invstd ; scaleshift[64+c] = beta - mean*scale
// ---------------------------------------------------------------------------
__global__ void stats_final(const float* __restrict__ part,
                            const float* __restrict__ gamma,
                            const float* __restrict__ beta,
                            float* __restrict__ scaleshift) {
  const int c = threadIdx.x;  // 0..63
  float S = 0.f, S2 = 0.f;
#pragma unroll
  for (int b = 0; b < B_; ++b) {
    S  += part[b * OUT_C_ + c];
    S2 += part[512 + b * OUT_C_ + c];
  }
  const float inv_n = 1.0f / (float)(B_ * OUT_L_ * T_);  // 1/131072
  const float mean = S * inv_n;
  const float var  = S2 * inv_n - mean * mean;
  const float inv  = rsqrtf(var + EPS_);
  const float sc   = gamma[c] * inv;
  scaleshift[c]        = sc;
  scaleshift[64 + c]   = beta[c] - mean * sc;
}

// ---------------------------------------------------------------------------
// Kernel 4: BN apply + PReLU, in place, float4 vectorized.
// ---------------------------------------------------------------------------
__global__ __launch_bounds__(256) void bn_prelu(
    float* __restrict__ out, const float* __restrict__ scaleshift,
    const float* __restrict__ alpha) {
  const float a = alpha[0];
  constexpr size_t N4 = (size_t)B_ * OUT_C_ * OUT_L_ * T_ / 4;  // 2097152
  float4* p = (float4*)out;
  for (size_t i = (size_t)blockIdx.x * 256 + threadIdx.x; i < N4;
       i += (size_t)gridDim.x * 256) {
    // channel of this float4: flat = 4*i ; c = (flat >> 14) & 63 (L*T=16384)
    const int c = (int)((i >> 12) & 63);
    const float sc = scaleshift[c];
    const float sh = scaleshift[64 + c];
    float4 v = p[i];
    v.x = v.x * sc + sh; v.x = (v.x >= 0.f) ? v.x : a * v.x;
    v.y = v.y * sc + sh; v.y = (v.y >= 0.f) ? v.y : a * v.y;
    v.z = v.z * sc + sh; v.z = (v.z >= 0.f) ? v.z : a * v.z;
    v.w = v.w * sc + sh; v.w = (v.w >= 0.f) ? v.w : a * v.w;
    p[i] = v;
  }
}

extern "C" void kernel_launch(void* const* d_in, const int* in_sizes, int n_in,
                              void* d_out, int out_size, void* d_ws, size_t ws_size,
                              hipStream_t stream) {
  const float* x     = (const float*)d_in[0];
  const float* w     = (const float*)d_in[1];
  const float* bias  = (const float*)d_in[2];
  const float* gamma = (const float*)d_in[3];
  const float* beta  = (const float*)d_in[4];
  const float* alpha = (const float*)d_in[5];
  float* out = (float*)d_out;
  float* ws  = (float*)d_ws;  // [0..1023] partials, [1024..1151] scale/shift

  conv_kernel<<<dim3(B_ * OUT_L_), dim3(256), 0, stream>>>(x, w, bias, out);
  stats_partial<<<dim3(B_ * OUT_C_), dim3(256), 0, stream>>>(out, ws);
  stats_final<<<dim3(1), dim3(64), 0, stream>>>(ws, gamma, beta, ws + 1024);
  bn_prelu<<<dim3(2048), dim3(256), 0, stream>>>(out, ws + 1024, alpha);
}

// Round 2
// 239.557 us; speedup vs baseline: 3.6619x; 3.6619x over previous
//
#include <hip/hip_runtime.h>

// Problem constants
constexpr int B_    = 8;
constexpr int IN_C_ = 64;
constexpr int IN_L_ = 64;
constexpr int T_    = 256;
constexpr int OUT_C_ = 64;
constexpr int OUT_L_ = 64;
constexpr float EPS_ = 1e-5f;

// ws layout (floats): [0 .. 65536) per-block partial stats, [65536 .. 65664) scale/shift
constexpr int WS_PART_ = 0;
constexpr int WS_SS_   = 65536;

// ---------------------------------------------------------------------------
// Kernel 1: locally-connected 3x3 conv + bias + fused BN partial stats.
// grid = B * OUT_L * 4 (2048 blocks); block = 256 threads (thread = t).
// Block handles (b, l, cg): 16 output channels [cg*16, cg*16+16).
// Weight slice w[:, cg*16..+16, l] staged in LDS (36 KB); inner loop is
// broadcast ds_read_b128 + 16 v_fmac_f32 per tap -> FMA-issue bound.
// Epilogue: bias add, store, and per-block sum/sumsq partials to ws.
// ---------------------------------------------------------------------------
__global__ __launch_bounds__(256) void conv_kernel(
    const float* __restrict__ x, const float* __restrict__ w,
    const float* __restrict__ bias, float* __restrict__ out,
    float* __restrict__ part) {
  const int bid = blockIdx.x;          // b*256 + l*4 + cg
  const int cg = bid & 3;
  const int l  = (bid >> 2) & 63;
  const int b  = bid >> 8;
  const int t  = threadIdx.x;          // 0..255
  const int cbase = cg * 16;

  // ---- stage weight slice into LDS: lw[k*16 + cl] = w[(k*64 + cbase+cl)*64 + l]
  __shared__ float lw[576 * 16];       // 36 KB
  for (int idx = t; idx < 576 * 16; idx += 256) {
    const int k  = idx >> 4;
    const int cl = idx & 15;
    lw[idx] = w[((size_t)(k * OUT_C_ + cbase + cl)) * OUT_L_ + l];
  }
  __syncthreads();

  float acc[16];
#pragma unroll
  for (int c = 0; c < 16; ++c) acc[c] = 0.f;

  const bool l0 = (l >= 1);
  const bool l2 = (l + 1 < IN_L_);
  const bool t0 = (t >= 1);
  const bool t2 = (t + 1 < T_);

  for (int ic = 0; ic < IN_C_; ++ic) {
    const float* xr = x + (((size_t)(b * IN_C_ + ic)) * IN_L_ + l) * T_ + t;
    float xv[9];
    xv[0] = (l0 && t0) ? xr[-T_ - 1] : 0.f;
    xv[1] =  l0        ? xr[-T_    ] : 0.f;
    xv[2] = (l0 && t2) ? xr[-T_ + 1] : 0.f;
    xv[3] =  t0        ? xr[-1     ] : 0.f;
    xv[4] =              xr[ 0     ];
    xv[5] =  t2        ? xr[ 1     ] : 0.f;
    xv[6] = (l2 && t0) ? xr[ T_ - 1] : 0.f;
    xv[7] =  l2        ? xr[ T_    ] : 0.f;
    xv[8] = (l2 && t2) ? xr[ T_ + 1] : 0.f;

    const int base = ic * 9 * 16;
#pragma unroll
    for (int kk = 0; kk < 9; ++kk) {
      const float xvk = xv[kk];
      const float* wk = &lw[base + kk * 16];
#pragma unroll
      for (int c = 0; c < 16; ++c) {
        acc[c] = fmaf(xvk, wk[c], acc[c]);
      }
    }
  }

  // ---- epilogue: bias, store, fused partial stats
  const int wid  = t >> 6;
  const int lane = t & 63;
  __shared__ float ls[4][16], ls2[4][16];

  const size_t obase = (((size_t)(b * OUT_C_ + cbase)) * OUT_L_ + l) * T_ + t;
#pragma unroll
  for (int c = 0; c < 16; ++c) {
    float v = acc[c] + bias[(cbase + c) * OUT_L_ + l];
    out[obase + (size_t)c * (OUT_L_ * T_)] = v;
    float s = v, s2 = v * v;
#pragma unroll
    for (int off = 32; off; off >>= 1) {
      s  += __shfl_down(s, off);
      s2 += __shfl_down(s2, off);
    }
    if (lane == 0) { ls[wid][c] = s; ls2[wid][c] = s2; }
  }
  __syncthreads();
  if (t < 16) {
    part[(size_t)bid * 32 + t] = ls[0][t] + ls[1][t] + ls[2][t] + ls[3][t];
  } else if (t < 32) {
    const int c = t - 16;
    part[(size_t)bid * 32 + 16 + c] = ls2[0][c] + ls2[1][c] + ls2[2][c] + ls2[3][c];
  }
}

// ---------------------------------------------------------------------------
// Kernel 2: finalize per-channel scale/shift. 64 blocks (one per channel),
// 64 threads each. Reduces 512 per-block partials.
// ---------------------------------------------------------------------------
__global__ __launch_bounds__(64) void stats_final(
    const float* __restrict__ part, const float* __restrict__ gamma,
    const float* __restrict__ beta, float* __restrict__ scaleshift) {
  const int C = blockIdx.x;      // 0..63
  const int cg = C >> 4, cloc = C & 15;
  const int t = threadIdx.x;     // 0..63
  float s = 0.f, s2 = 0.f;
  for (int i = t; i < 512; i += 64) {   // i = b*64 + l
    const int b = i >> 6, l = i & 63;
    const size_t idx = ((size_t)(b * 256 + l * 4 + cg)) * 32;
    s  += part[idx + cloc];
    s2 += part[idx + 16 + cloc];
  }
#pragma unroll
  for (int off = 32; off; off >>= 1) {
    s  += __shfl_down(s, off);
    s2 += __shfl_down(s2, off);
  }
  if (t == 0) {
    const float inv_n = 1.0f / (float)(B_ * OUT_L_ * T_);
    const float mean = s * inv_n;
    const float var  = s2 * inv_n - mean * mean;
    const float inv  = rsqrtf(var + EPS_);
    const float sc   = gamma[C] * inv;
    scaleshift[C]      = sc;
    scaleshift[64 + C] = beta[C] - mean * sc;
  }
}

// ---------------------------------------------------------------------------
// Kernel 3: BN apply + PReLU, in place, float4 vectorized.
// ---------------------------------------------------------------------------
__global__ __launch_bounds__(256) void bn_prelu(
    float* __restrict__ out, const float* __restrict__ scaleshift,
    const float* __restrict__ alpha) {
  const float a = alpha[0];
  constexpr size_t N4 = (size_t)B_ * OUT_C_ * OUT_L_ * T_ / 4;  // 2097152
  float4* p = (float4*)out;
  for (size_t i = (size_t)blockIdx.x * 256 + threadIdx.x; i < N4;
       i += (size_t)gridDim.x * 256) {
    const int c = (int)((i >> 12) & 63);   // L*T/4 = 4096 float4 per channel
    const float sc = scaleshift[c];
    const float sh = scaleshift[64 + c];
    float4 v = p[i];
    v.x = v.x * sc + sh; v.x = (v.x >= 0.f) ? v.x : a * v.x;
    v.y = v.y * sc + sh; v.y = (v.y >= 0.f) ? v.y : a * v.y;
    v.z = v.z * sc + sh; v.z = (v.z >= 0.f) ? v.z : a * v.z;
    v.w = v.w * sc + sh; v.w = (v.w >= 0.f) ? v.w : a * v.w;
    p[i] = v;
  }
}

extern "C" void kernel_launch(void* const* d_in, const int* in_sizes, int n_in,
                              void* d_out, int out_size, void* d_ws, size_t ws_size,
                              hipStream_t stream) {
  const float* x     = (const float*)d_in[0];
  const float* w     = (const float*)d_in[1];
  const float* bias  = (const float*)d_in[2];
  const float* gamma = (const float*)d_in[3];
  const float* beta  = (const float*)d_in[4];
  const float* alpha = (const float*)d_in[5];
  float* out  = (float*)d_out;
  float* ws   = (float*)d_ws;
  float* part = ws + WS_PART_;
  float* ss   = ws + WS_SS_;

  conv_kernel<<<dim3(B_ * OUT_L_ * 4), dim3(256), 0, stream>>>(x, w, bias, out, part);
  stats_final<<<dim3(64), dim3(64), 0, stream>>>(part, gamma, beta, ss);
  bn_prelu<<<dim3(2048), dim3(256), 0, stream>>>(out, ss, alpha);
}

// Round 4
// 98.280 us; speedup vs baseline: 8.9258x; 2.4375x over previous
//
#include <hip/hip_runtime.h>

typedef __attribute__((ext_vector_type(8))) short short8;
typedef __attribute__((ext_vector_type(4))) float f32x4;

// Problem constants
constexpr int B_ = 8, IN_C_ = 64, IN_L_ = 64, T_ = 256, OUT_C_ = 64, OUT_L_ = 64;
constexpr float EPS_ = 1e-5f;

// xT_pad: bf16 [8 b][66 lp][258 tp][64 ic]; lp = l+1, tp = t+1, halo rows/cols = 0
constexpr int XT_LP = 66, XT_TP = 258, XT_IC = 64;
constexpr int XT_LSTRIDE = XT_TP * XT_IC;            // 16512 elems
constexpr int XT_BSTRIDE = XT_LP * XT_LSTRIDE;       // 1,089,792 elems
constexpr size_t XT_ELEMS = (size_t)B_ * XT_BSTRIDE; // 8,718,336
constexpr size_t XT_BYTES = XT_ELEMS * 2;            // 17,436,672
// wT2: bf16 [64 l][9 tap][64 c][64 ic]
constexpr size_t WT2_ELEMS = 64ull * 9 * 64 * 64;    // 2,359,296
constexpr size_t WT2_OFF_B = XT_BYTES;
constexpr size_t PART_OFF_B = WT2_OFF_B + WT2_ELEMS * 2;   // 22,155,264
constexpr size_t SS_OFF_B = PART_OFF_B + 512ull * 128 * 4; // 22,417,408
constexpr size_t WS_NEED = SS_OFF_B + 128 * 4;             // 22,417,920

__device__ __forceinline__ unsigned short f2bf(float f) {
  unsigned u = __float_as_uint(f);
  return (unsigned short)((u + 0x7fffu + ((u >> 16) & 1u)) >> 16);
}

// ---------------------------------------------------------------------------
// Prepass 1: x fp32 [b][ic][l][t] -> xT bf16 [b][l+1][t+1][ic] (LDS transpose).
// grid = 8*64*2 = 1024 blocks; block (b, l, t-half of 128).
// ---------------------------------------------------------------------------
__global__ __launch_bounds__(256) void xprep(const float* __restrict__ x,
                                             unsigned short* __restrict__ xT) {
  const int bid = blockIdx.x;
  const int th = bid & 1, l = (bid >> 1) & 63, b = bid >> 7;
  const int tid = threadIdx.x;
  const int t0 = th * 128;
  __shared__ unsigned short ls[64][132];  // [ic][t-local], pad keeps rows 8B-aligned
  {
    const int ic = tid >> 2, q = tid & 3;
    const float4* src = (const float4*)(x + (((size_t)(b * 64 + ic) * 64 + l) * 256 + t0));
#pragma unroll
    for (int e = 0; e < 8; ++e) {
      float4 v = src[q * 8 + e];
      const int toff = (q * 8 + e) * 4;
      unsigned d0 = f2bf(v.x) | ((unsigned)f2bf(v.y) << 16);
      unsigned d1 = f2bf(v.z) | ((unsigned)f2bf(v.w) << 16);
      *(uint2*)&ls[ic][toff] = make_uint2(d0, d1);
    }
  }
  __syncthreads();
  {
    const int tl = tid >> 1, h = tid & 1;  // t-row, ic-half
    unsigned d[16];
#pragma unroll
    for (int k = 0; k < 16; ++k) {
      unsigned short a = ls[h * 32 + 2 * k][tl];
      unsigned short c = ls[h * 32 + 2 * k + 1][tl];
      d[k] = a | ((unsigned)c << 16);
    }
    unsigned short* dst =
        xT + ((size_t)(b * XT_LP + l + 1) * XT_TP + (t0 + tl + 1)) * XT_IC + h * 32;
    uint4* dv = (uint4*)dst;
    dv[0] = make_uint4(d[0], d[1], d[2], d[3]);
    dv[1] = make_uint4(d[4], d[5], d[6], d[7]);
    dv[2] = make_uint4(d[8], d[9], d[10], d[11]);
    dv[3] = make_uint4(d[12], d[13], d[14], d[15]);
  }
}

// ---------------------------------------------------------------------------
// Prepass 2: w fp32 [k=ic*9+tap][c][l] -> wT2 bf16 [l][tap][c][ic].
// One thread per (l,tap,c): 64 strided reads, one contiguous 128B row write.
// (Round-3 fix: exact lt/9, lt%9 — the (lt*57)>>9 magic was wrong for
//  lt>=~560, producing l=64/tap=-1 -> OOB read -> device abort.)
// ---------------------------------------------------------------------------
__global__ __launch_bounds__(256) void wprep(const float* __restrict__ w,
                                             unsigned short* __restrict__ wT2) {
  const int g = blockIdx.x * 256 + threadIdx.x;  // 0..36863
  const int c = g & 63;
  const int lt = g >> 6;           // l*9 + tap, 0..575
  const int l = lt / 9;
  const int tap = lt % 9;
  unsigned short* dst = wT2 + ((size_t)lt * 64 + c) * 64;
  const float* src = w + ((size_t)tap * 64 + c) * 64 + l;  // + ic*9*4096
#pragma unroll
  for (int ic0 = 0; ic0 < 64; ic0 += 8) {
    unsigned d[4];
#pragma unroll
    for (int k = 0; k < 4; ++k) {
      float a = src[(size_t)(ic0 + 2 * k) * 9 * 4096];
      float c2 = src[(size_t)(ic0 + 2 * k + 1) * 9 * 4096];
      d[k] = f2bf(a) | ((unsigned)f2bf(c2) << 16);
    }
    *(uint4*)(dst + ic0) = make_uint4(d[0], d[1], d[2], d[3]);
  }
}

// ---------------------------------------------------------------------------
// Main conv: per (b,l) block, 256x64 GEMM over K=576 via 9 taps x 2 K-halves.
// 4 waves x (4 m-frags x 4 n-frags) of mfma_f32_16x16x32_bf16.
// Operands loaded straight from global (L2-resident), no LDS in main loop.
// Epilogue: bias add, store, fused per-channel sum/sumsq partials.
// ---------------------------------------------------------------------------
__global__ __launch_bounds__(256, 2) void conv_mfma(
    const unsigned short* __restrict__ xT, const unsigned short* __restrict__ wT2,
    const float* __restrict__ bias, float* __restrict__ out,
    float* __restrict__ part) {
  const int bid = blockIdx.x;  // b*64 + l
  const int b = bid >> 6, l = bid & 63;
  const int tid = threadIdx.x;
  const int wid = tid >> 6, ln = tid & 63;
  const int lc = ln & 15, lg = ln >> 4;
  const int t_base = wid * 64;

  const unsigned short* xA = xT + (size_t)(b * XT_LP + l) * XT_LSTRIDE + lg * 8;
  const unsigned short* wB = wT2 + (size_t)l * 9 * 4096 + lc * 64 + lg * 8;

  int aoff[4];
#pragma unroll
  for (int mi = 0; mi < 4; ++mi) aoff[mi] = (t_base + mi * 16 + lc) * XT_IC;

  f32x4 acc[4][4] = {};

#pragma unroll
  for (int tap = 0; tap < 9; ++tap) {
    const int i = tap / 3, j = tap % 3;
#pragma unroll
    for (int kb = 0; kb < 2; ++kb) {
      short8 af[4], bfr[4];
#pragma unroll
      for (int mi = 0; mi < 4; ++mi)
        af[mi] = *(const short8*)(xA + aoff[mi] + i * XT_LSTRIDE + j * XT_IC + kb * 32);
#pragma unroll
      for (int ni = 0; ni < 4; ++ni)
        bfr[ni] = *(const short8*)(wB + tap * 4096 + ni * 1024 + kb * 32);
#pragma unroll
      for (int mi = 0; mi < 4; ++mi)
#pragma unroll
        for (int ni = 0; ni < 4; ++ni)
          acc[mi][ni] =
              __builtin_amdgcn_mfma_f32_16x16x32_bf16(af[mi], bfr[ni], acc[mi][ni], 0, 0, 0);
    }
  }

  // epilogue: bias + store + fused stats. D: row(t)=(lg*4+r)+mi*16, col(c)=ni*16+lc
  __shared__ float sm[4][4][16][2];
#pragma unroll
  for (int ni = 0; ni < 4; ++ni) {
    const int c = ni * 16 + lc;
    const float bv = bias[c * 64 + l];
    float s = 0.f, s2 = 0.f;
    float* op = out + ((size_t)(b * 64 + c) * 64 + l) * 256;
#pragma unroll
    for (int mi = 0; mi < 4; ++mi) {
#pragma unroll
      for (int r = 0; r < 4; ++r) {
        float v = acc[mi][ni][r] + bv;
        op[t_base + mi * 16 + lg * 4 + r] = v;
        s += v;
        s2 += v * v;
      }
    }
    s += __shfl_xor(s, 16);  s += __shfl_xor(s, 32);
    s2 += __shfl_xor(s2, 16); s2 += __shfl_xor(s2, 32);
    if (lg == 0) { sm[wid][ni][lc][0] = s; sm[wid][ni][lc][1] = s2; }
  }
  __syncthreads();
  if (tid < 128) {
    const int sel = tid >> 6, cc = tid & 63;
    const int ni = cc >> 4, lc2 = cc & 15;
    part[(size_t)bid * 128 + sel * 64 + cc] =
        sm[0][ni][lc2][sel] + sm[1][ni][lc2][sel] + sm[2][ni][lc2][sel] + sm[3][ni][lc2][sel];
  }
}

// ---------------------------------------------------------------------------
// Finalize per-channel scale/shift from 512 block-partials.
// ---------------------------------------------------------------------------
__global__ __launch_bounds__(256) void stats_final_mf(
    const float* __restrict__ part, const float* __restrict__ gamma,
    const float* __restrict__ beta, float* __restrict__ ss) {
  const int c = blockIdx.x;  // 0..63
  const int tid = threadIdx.x;
  float s = 0.f, s2 = 0.f;
  for (int blk = tid; blk < 512; blk += 256) {
    s += part[(size_t)blk * 128 + c];
    s2 += part[(size_t)blk * 128 + 64 + c];
  }
#pragma unroll
  for (int off = 32; off; off >>= 1) {
    s += __shfl_down(s, off);
    s2 += __shfl_down(s2, off);
  }
  __shared__ float r0[4], r1[4];
  const int wid = tid >> 6, lane = tid & 63;
  if (lane == 0) { r0[wid] = s; r1[wid] = s2; }
  __syncthreads();
  if (tid == 0) {
    float S = r0[0] + r0[1] + r0[2] + r0[3];
    float S2 = r1[0] + r1[1] + r1[2] + r1[3];
    const float inv_n = 1.0f / 131072.f;
    float mean = S * inv_n;
    float var = S2 * inv_n - mean * mean;
    float inv = rsqrtf(var + EPS_);
    float sc = gamma[c] * inv;
    ss[c] = sc;
    ss[64 + c] = beta[c] - mean * sc;
  }
}

// ---------------------------------------------------------------------------
// BN apply + PReLU, in place, float4 vectorized.
// ---------------------------------------------------------------------------
__global__ __launch_bounds__(256) void bn_prelu(
    float* __restrict__ out, const float* __restrict__ scaleshift,
    const float* __restrict__ alpha) {
  const float a = alpha[0];
  constexpr size_t N4 = (size_t)B_ * OUT_C_ * OUT_L_ * T_ / 4;  // 2097152
  float4* p = (float4*)out;
  for (size_t i = (size_t)blockIdx.x * 256 + threadIdx.x; i < N4;
       i += (size_t)gridDim.x * 256) {
    const int c = (int)((i >> 12) & 63);
    const float sc = scaleshift[c];
    const float sh = scaleshift[64 + c];
    float4 v = p[i];
    v.x = v.x * sc + sh; v.x = (v.x >= 0.f) ? v.x : a * v.x;
    v.y = v.y * sc + sh; v.y = (v.y >= 0.f) ? v.y : a * v.y;
    v.z = v.z * sc + sh; v.z = (v.z >= 0.f) ? v.z : a * v.z;
    v.w = v.w * sc + sh; v.w = (v.w >= 0.f) ? v.w : a * v.w;
    p[i] = v;
  }
}

// ======================= Fallback (round-2 VALU path) =======================
__global__ __launch_bounds__(256) void conv_fb(
    const float* __restrict__ x, const float* __restrict__ w,
    const float* __restrict__ bias, float* __restrict__ out,
    float* __restrict__ part) {
  const int bid = blockIdx.x;
  const int cg = bid & 3;
  const int l = (bid >> 2) & 63;
  const int b = bid >> 8;
  const int t = threadIdx.x;
  const int cbase = cg * 16;
  __shared__ float lw[576 * 16];
  for (int idx = t; idx < 576 * 16; idx += 256) {
    const int k = idx >> 4, cl = idx & 15;
    lw[idx] = w[((size_t)(k * OUT_C_ + cbase + cl)) * OUT_L_ + l];
  }
  __syncthreads();
  float acc[16];
#pragma unroll
  for (int c = 0; c < 16; ++c) acc[c] = 0.f;
  const bool l0 = (l >= 1), l2 = (l + 1 < IN_L_);
  const bool t0 = (t >= 1), t2 = (t + 1 < T_);
  for (int ic = 0; ic < IN_C_; ++ic) {
    const float* xr = x + (((size_t)(b * IN_C_ + ic)) * IN_L_ + l) * T_ + t;
    float xv[9];
    xv[0] = (l0 && t0) ? xr[-T_ - 1] : 0.f;
    xv[1] = l0 ? xr[-T_] : 0.f;
    xv[2] = (l0 && t2) ? xr[-T_ + 1] : 0.f;
    xv[3] = t0 ? xr[-1] : 0.f;
    xv[4] = xr[0];
    xv[5] = t2 ? xr[1] : 0.f;
    xv[6] = (l2 && t0) ? xr[T_ - 1] : 0.f;
    xv[7] = l2 ? xr[T_] : 0.f;
    xv[8] = (l2 && t2) ? xr[T_ + 1] : 0.f;
    const int base = ic * 9 * 16;
#pragma unroll
    for (int kk = 0; kk < 9; ++kk) {
      const float xvk = xv[kk];
      const float* wk = &lw[base + kk * 16];
#pragma unroll
      for (int c = 0; c < 16; ++c) acc[c] = fmaf(xvk, wk[c], acc[c]);
    }
  }
  const int wid = t >> 6, lane = t & 63;
  __shared__ float ls[4][16], ls2[4][16];
  const size_t obase = (((size_t)(b * OUT_C_ + cbase)) * OUT_L_ + l) * T_ + t;
#pragma unroll
  for (int c = 0; c < 16; ++c) {
    float v = acc[c] + bias[(cbase + c) * OUT_L_ + l];
    out[obase + (size_t)c * (OUT_L_ * T_)] = v;
    float s = v, s2 = v * v;
#pragma unroll
    for (int off = 32; off; off >>= 1) {
      s += __shfl_down(s, off);
      s2 += __shfl_down(s2, off);
    }
    if (lane == 0) { ls[wid][c] = s; ls2[wid][c] = s2; }
  }
  __syncthreads();
  if (t < 16) {
    part[(size_t)bid * 32 + t] = ls[0][t] + ls[1][t] + ls[2][t] + ls[3][t];
  } else if (t < 32) {
    const int c = t - 16;
    part[(size_t)bid * 32 + 16 + c] = ls2[0][c] + ls2[1][c] + ls2[2][c] + ls2[3][c];
  }
}

__global__ __launch_bounds__(64) void stats_final_fb(
    const float* __restrict__ part, const float* __restrict__ gamma,
    const float* __restrict__ beta, float* __restrict__ scaleshift) {
  const int C = blockIdx.x;
  const int cg = C >> 4, cloc = C & 15;
  const int t = threadIdx.x;
  float s = 0.f, s2 = 0.f;
  for (int i = t; i < 512; i += 64) {
    const int b = i >> 6, l = i & 63;
    const size_t idx = ((size_t)(b * 256 + l * 4 + cg)) * 32;
    s += part[idx + cloc];
    s2 += part[idx + 16 + cloc];
  }
#pragma unroll
  for (int off = 32; off; off >>= 1) {
    s += __shfl_down(s, off);
    s2 += __shfl_down(s2, off);
  }
  if (t == 0) {
    const float inv_n = 1.0f / (float)(B_ * OUT_L_ * T_);
    const float mean = s * inv_n;
    const float var = s2 * inv_n - mean * mean;
    const float inv = rsqrtf(var + EPS_);
    const float sc = gamma[C] * inv;
    scaleshift[C] = sc;
    scaleshift[64 + C] = beta[C] - mean * sc;
  }
}

extern "C" void kernel_launch(void* const* d_in, const int* in_sizes, int n_in,
                              void* d_out, int out_size, void* d_ws, size_t ws_size,
                              hipStream_t stream) {
  const float* x = (const float*)d_in[0];
  const float* w = (const float*)d_in[1];
  const float* bias = (const float*)d_in[2];
  const float* gamma = (const float*)d_in[3];
  const float* beta = (const float*)d_in[4];
  const float* alpha = (const float*)d_in[5];
  float* out = (float*)d_out;

  if (ws_size >= WS_NEED) {
    unsigned short* xT = (unsigned short*)d_ws;
    unsigned short* wT2 = (unsigned short*)((char*)d_ws + WT2_OFF_B);
    float* part = (float*)((char*)d_ws + PART_OFF_B);
    float* ssb = (float*)((char*)d_ws + SS_OFF_B);
    hipMemsetAsync(d_ws, 0, XT_BYTES, stream);  // zero halos (interior overwritten)
    xprep<<<dim3(1024), dim3(256), 0, stream>>>(x, xT);
    wprep<<<dim3(144), dim3(256), 0, stream>>>(w, wT2);
    conv_mfma<<<dim3(512), dim3(256), 0, stream>>>(xT, wT2, bias, out, part);
    stats_final_mf<<<dim3(64), dim3(256), 0, stream>>>(part, gamma, beta, ssb);
    bn_prelu<<<dim3(2048), dim3(256), 0, stream>>>(out, ssb, alpha);
  } else {
    float* ws = (float*)d_ws;
    float* part = ws;
    float* ss = ws + 65536;
    conv_fb<<<dim3(B_ * OUT_L_ * 4), dim3(256), 0, stream>>>(x, w, bias, out, part);
    stats_final_fb<<<dim3(64), dim3(64), 0, stream>>>(part, gamma, beta, ss);
    bn_prelu<<<dim3(2048), dim3(256), 0, stream>>>(out, ss, alpha);
  }
}